// Round 15
// baseline (69.121 us; speedup 1.0000x reference)
//
#include <hip/hip_runtime.h>

#define LOG2E 1.4426950408889634f
#define TWO_LOG2E 2.885390081777927f

__device__ __forceinline__ float fast_exp2(float x) { return __builtin_amdgcn_exp2f(x); }
__device__ __forceinline__ float fast_rcp(float x)  { return __builtin_amdgcn_rcpf(x); }

// paired-rcp: s0/A + s1/B with A=q0*k0+1, B=q1*k1+1
__device__ __forceinline__ void term2(float s0, float s1, float qx, float qy,
                                      float kx, float ky, float& acc) {
    const float A = fmaf(qx, kx, 1.f);
    const float B = fmaf(qy, ky, 1.f);
    acc = fmaf(fmaf(s1, A, s0 * B), fast_rcp(A * B), acc);
}

// ---------------------------------------------------------------------------
// K1: projections + exp transform (unchanged).
// ---------------------------------------------------------------------------
__global__ __launch_bounds__(256) void proj_kernel(
    const float* __restrict__ query, const float* __restrict__ value,
    const float* __restrict__ Wq, const float* __restrict__ Wv,
    float* __restrict__ eq, float* __restrict__ ek)
{
    __shared__ float in_lds[8 * 256];
    const int t = threadIdx.x;
    const int row0 = blockIdx.x * 8;
    const float* src; const float* W; float* dst;
    if (row0 < 2048) { src = query + (size_t)row0 * 256; W = Wq; dst = eq + (size_t)row0 * 256; }
    else { const int r = row0 - 2048; src = value + (size_t)r * 256; W = Wv; dst = ek + (size_t)r * 256; }

    const float4* s4 = (const float4*)src;
    float4* l4 = (float4*)in_lds;
    l4[t] = s4[t];
    l4[t + 256] = s4[t + 256];
    __syncthreads();

    float acc[8];
#pragma unroll
    for (int r = 0; r < 8; ++r) acc[r] = 0.f;

    for (int d = 0; d < 256; d += 4) {
        const float w0 = W[(d + 0) * 256 + t];
        const float w1 = W[(d + 1) * 256 + t];
        const float w2 = W[(d + 2) * 256 + t];
        const float w3 = W[(d + 3) * 256 + t];
#pragma unroll
        for (int r = 0; r < 8; ++r) {
            const float4 v = *(const float4*)&in_lds[r * 256 + d];
            acc[r] = fmaf(v.x, w0, acc[r]);
            acc[r] = fmaf(v.y, w1, acc[r]);
            acc[r] = fmaf(v.z, w2, acc[r]);
            acc[r] = fmaf(v.w, w3, acc[r]);
        }
    }
#pragma unroll
    for (int r = 0; r < 8; ++r) dst[r * 256 + t] = fast_exp2(acc[r] * TWO_LOG2E);
}

// ---------------------------------------------------------------------------
// K2: FUSED scores + softmax + PV, v4 (= v3 octant structure, 74.7KB LDS ->
// 2 blocks/CU). ek tile staged in two 128-d halves (buffer 64x132 = 33.8KB).
// Per half h, wave w covers d-sector 128h + [16w, 16w+16); accumulators
// carried across halves -> identical instruction totals to v3; pslot combine
// once per tile. Rotate swizzle (verified 0 conflicts in R13).
// Block = (b, 8 q-rows), 512 thr, grid (64,4) = 256 blocks.
// ---------------------------------------------------------------------------
#define EKH_ST 132
#define EQ_ST 260
#define SS_ST 520
__global__ __launch_bounds__(512) void fused_kernel(
    const float* __restrict__ eq, const float* __restrict__ ek,
    const float* __restrict__ scale, const float* __restrict__ value,
    float* __restrict__ attn, float* __restrict__ out)
{
    __shared__ float ek_lds[64 * EKH_ST];   // 33.8KB; reduce buffer in Phase D
    __shared__ float eq_lds[8 * EQ_ST];     // 8.3KB (full 256 d)
    __shared__ float sc_lds[256];
    __shared__ float s_tile[8 * SS_ST];     // 16.6KB raw scores -> raw exp
    __shared__ float pslot[8 * SS_ST];      // 16.6KB octant partials
    __shared__ float inv_lds[8];

    const int t = threadIdx.x;
    const int w = t >> 6, lane = t & 63;
    const int qp = lane >> 4;               // q-pair 0..3
    const int kq = lane & 15;               // k-quad 0..15
    const int qt = blockIdx.x, b = blockIdx.y;
    const int q0 = qt * 8;

    const float4* ekb4 = (const float4*)(ek + (size_t)(b * 512) * 256);

    // prologue: stage eq (8x256) and scale
    {
        const int row = t >> 6, c = t & 63;
        const float4 v = ((const float4*)(eq + (size_t)(b * 512 + q0) * 256))[row * 64 + c];
        *(float4*)&eq_lds[row * EQ_ST + 4 * c] = v;
    }
    if (t < 256) sc_lds[t] = -2.f * scale[t];

    // ---- Phase A: 8 k-tiles x 2 d-halves ----
    for (int tt = 0; tt < 8; ++tt) {
        float a00 = 0.f, a01 = 0.f, a02 = 0.f, a03 = 0.f;
        float a10 = 0.f, a11 = 0.f, a12 = 0.f, a13 = 0.f;

#pragma unroll
        for (int h = 0; h < 2; ++h) {
            __syncthreads();                // prev reads (or prologue) done
            // stage 64 rows x 128 d of half h, rotate-swizzled
#pragma unroll
            for (int l = 0; l < 4; ++l) {
                const int idx = t + 512 * l;            // 0..2047
                const int row = idx >> 5, c = idx & 31;
                const int cc = (c + (row >> 2)) & 31;
                *(float4*)&ek_lds[row * EKH_ST + 4 * cc] =
                    ekb4[(size_t)(64 * tt + row) * 64 + 32 * h + c];
            }
            __syncthreads();

#pragma unroll
            for (int it = 0; it < 4; ++it) {
                const int dl = 16 * w + 4 * it;         // local d in half
                const int dg = 128 * h + dl;            // global d
                const float4 sv  = *(const float4*)&sc_lds[dg];
                const float4 q0v = *(const float4*)&eq_lds[(2 * qp + 0) * EQ_ST + dg];
                const float4 q1v = *(const float4*)&eq_lds[(2 * qp + 1) * EQ_ST + dg];
                const int cc = 4 * (((dl >> 2) + kq) & 31);
                const float4 k0 = *(const float4*)&ek_lds[(4 * kq + 0) * EKH_ST + cc];
                const float4 k1 = *(const float4*)&ek_lds[(4 * kq + 1) * EKH_ST + cc];
                const float4 k2 = *(const float4*)&ek_lds[(4 * kq + 2) * EKH_ST + cc];
                const float4 k3 = *(const float4*)&ek_lds[(4 * kq + 3) * EKH_ST + cc];

                term2(sv.x, sv.y, q0v.x, q0v.y, k0.x, k0.y, a00);
                term2(sv.x, sv.y, q0v.x, q0v.y, k1.x, k1.y, a01);
                term2(sv.x, sv.y, q0v.x, q0v.y, k2.x, k2.y, a02);
                term2(sv.x, sv.y, q0v.x, q0v.y, k3.x, k3.y, a03);
                term2(sv.x, sv.y, q1v.x, q1v.y, k0.x, k0.y, a10);
                term2(sv.x, sv.y, q1v.x, q1v.y, k1.x, k1.y, a11);
                term2(sv.x, sv.y, q1v.x, q1v.y, k2.x, k2.y, a12);
                term2(sv.x, sv.y, q1v.x, q1v.y, k3.x, k3.y, a13);

                term2(sv.z, sv.w, q0v.z, q0v.w, k0.z, k0.w, a00);
                term2(sv.z, sv.w, q0v.z, q0v.w, k1.z, k1.w, a01);
                term2(sv.z, sv.w, q0v.z, q0v.w, k2.z, k2.w, a02);
                term2(sv.z, sv.w, q0v.z, q0v.w, k3.z, k3.w, a03);
                term2(sv.z, sv.w, q1v.z, q1v.w, k0.z, k0.w, a10);
                term2(sv.z, sv.w, q1v.z, q1v.w, k1.z, k1.w, a11);
                term2(sv.z, sv.w, q1v.z, q1v.w, k2.z, k2.w, a12);
                term2(sv.z, sv.w, q1v.z, q1v.w, k3.z, k3.w, a13);
            }
        }

        // octant (d-sector) partials -> pslot[w][score]
        {
            float* ps = &pslot[w * SS_ST];
            const int s0i = (2 * qp + 0) * 64 + 4 * kq;
            const int s1i = (2 * qp + 1) * 64 + 4 * kq;
            ps[s0i + 0] = a00; ps[s0i + 1] = a01; ps[s0i + 2] = a02; ps[s0i + 3] = a03;
            ps[s1i + 0] = a10; ps[s1i + 1] = a11; ps[s1i + 2] = a12; ps[s1i + 3] = a13;
        }
        __syncthreads();
        // deterministic sum of 8 partials; thread t owns score t
        {
            float s = pslot[t];
#pragma unroll
            for (int o = 1; o < 8; ++o) s += pslot[o * SS_ST + t];
            s_tile[(t >> 6) * SS_ST + 64 * tt + (t & 63)] = s;
        }
        // next tile's first stage-barrier orders pslot reuse
    }
    __syncthreads();

    // ---- Phase B: softmax (wave w = q-row w), attn write ----
    float x[8];
    float m = -1e30f;
#pragma unroll
    for (int j = 0; j < 8; ++j) {
        x[j] = s_tile[w * SS_ST + 64 * j + lane];
        m = fmaxf(m, x[j]);
    }
#pragma unroll
    for (int off = 32; off; off >>= 1) m = fmaxf(m, __shfl_xor(m, off));

    float sum = 0.f;
#pragma unroll
    for (int j = 0; j < 8; ++j) { x[j] = fast_exp2((x[j] - m) * LOG2E); sum += x[j]; }
#pragma unroll
    for (int off = 32; off; off >>= 1) sum += __shfl_xor(sum, off);
    const float inv = fast_rcp(sum);

    float* arow = attn + (size_t)(b * 512 + q0 + w) * 512;
#pragma unroll
    for (int j = 0; j < 8; ++j) {
        s_tile[w * SS_ST + 64 * j + lane] = x[j];   // raw exp for PV
        arow[64 * j + lane] = x[j] * inv;
    }
    if (lane == 0) inv_lds[w] = inv;
    __syncthreads();

    // ---- Phase C: PV, wave w owns k in [64w, 64w+64) ----
    float4 acc[8];
#pragma unroll
    for (int r = 0; r < 8; ++r) acc[r] = make_float4(0.f, 0.f, 0.f, 0.f);

    const float* vbase = value + (size_t)(b * 512 + 64 * w) * 256;
    for (int k4 = 0; k4 < 64; k4 += 4) {
        const float4 v0 = *(const float4*)&vbase[(k4 + 0) * 256 + lane * 4];
        const float4 v1 = *(const float4*)&vbase[(k4 + 1) * 256 + lane * 4];
        const float4 v2 = *(const float4*)&vbase[(k4 + 2) * 256 + lane * 4];
        const float4 v3 = *(const float4*)&vbase[(k4 + 3) * 256 + lane * 4];
#pragma unroll
        for (int r = 0; r < 8; ++r) {
            const float4 s4 = *(const float4*)&s_tile[r * SS_ST + 64 * w + k4];
            acc[r].x = fmaf(s4.x, v0.x, acc[r].x); acc[r].y = fmaf(s4.x, v0.y, acc[r].y);
            acc[r].z = fmaf(s4.x, v0.z, acc[r].z); acc[r].w = fmaf(s4.x, v0.w, acc[r].w);
            acc[r].x = fmaf(s4.y, v1.x, acc[r].x); acc[r].y = fmaf(s4.y, v1.y, acc[r].y);
            acc[r].z = fmaf(s4.y, v1.z, acc[r].z); acc[r].w = fmaf(s4.y, v1.w, acc[r].w);
            acc[r].x = fmaf(s4.z, v2.x, acc[r].x); acc[r].y = fmaf(s4.z, v2.y, acc[r].y);
            acc[r].z = fmaf(s4.z, v2.z, acc[r].z); acc[r].w = fmaf(s4.z, v2.w, acc[r].w);
            acc[r].x = fmaf(s4.w, v3.x, acc[r].x); acc[r].y = fmaf(s4.w, v3.y, acc[r].y);
            acc[r].z = fmaf(s4.w, v3.z, acc[r].z); acc[r].w = fmaf(s4.w, v3.w, acc[r].w);
        }
    }

    // ---- Phase D: tree reduce 8 -> 1 (red = ek_lds, 8448 >= 8192 floats) ----
    float* red = ek_lds;
    if (w >= 4) {
#pragma unroll
        for (int r = 0; r < 8; ++r)
            *(float4*)&red[((w - 4) * 8 + r) * 256 + lane * 4] = acc[r];
    }
    __syncthreads();
    if (w < 4) {
#pragma unroll
        for (int r = 0; r < 8; ++r) {
            const float4 o = *(const float4*)&red[(w * 8 + r) * 256 + lane * 4];
            acc[r].x += o.x; acc[r].y += o.y; acc[r].z += o.z; acc[r].w += o.w;
        }
    }
    __syncthreads();
    if (w >= 2 && w < 4) {
#pragma unroll
        for (int r = 0; r < 8; ++r)
            *(float4*)&red[((w - 2) * 8 + r) * 256 + lane * 4] = acc[r];
    }
    __syncthreads();
    if (w < 2) {
#pragma unroll
        for (int r = 0; r < 8; ++r) {
            const float4 o = *(const float4*)&red[(w * 8 + r) * 256 + lane * 4];
            acc[r].x += o.x; acc[r].y += o.y; acc[r].z += o.z; acc[r].w += o.w;
        }
    }
    __syncthreads();
    if (w == 1) {
#pragma unroll
        for (int r = 0; r < 8; ++r)
            *(float4*)&red[r * 256 + lane * 4] = acc[r];
    }
    __syncthreads();
    if (w == 0) {
#pragma unroll
        for (int r = 0; r < 8; ++r) {
            const float4 o = *(const float4*)&red[r * 256 + lane * 4];
            const float iv = inv_lds[r];
            float4 res;
            res.x = (acc[r].x + o.x) * iv;
            res.y = (acc[r].y + o.y) * iv;
            res.z = (acc[r].z + o.z) * iv;
            res.w = (acc[r].w + o.w) * iv;
            *(float4*)&out[(size_t)(b * 512 + q0 + r) * 256 + lane * 4] = res;
        }
    }
}

extern "C" void kernel_launch(void* const* d_in, const int* in_sizes, int n_in,
                              void* d_out, int out_size, void* d_ws, size_t ws_size,
                              hipStream_t stream) {
    const float* query = (const float*)d_in[0];
    const float* value = (const float*)d_in[1];
    const float* Wq    = (const float*)d_in[2];
    const float* Wv    = (const float*)d_in[3];
    const float* scale = (const float*)d_in[4];

    float* out0 = (float*)d_out;                 // [4,512,256]
    float* attn = out0 + 4 * 512 * 256;          // [4,512,512]

    float* eq = (float*)d_ws;                    // [2048,256]
    float* ek = eq + 2048 * 256;                 // [2048,256]

    proj_kernel<<<512, 256, 0, stream>>>(query, value, Wq, Wv, eq, ek);
    fused_kernel<<<dim3(64, 4), 512, 0, stream>>>(eq, ek, scale, value, attn, out0);
}

// Round 16
// 67.585 us; speedup vs baseline: 1.0227x; 1.0227x over previous
//
#include <hip/hip_runtime.h>

#define LOG2E 1.4426950408889634f
#define TWO_LOG2E 2.885390081777927f

__device__ __forceinline__ float fast_exp2(float x) { return __builtin_amdgcn_exp2f(x); }
__device__ __forceinline__ float fast_rcp(float x)  { return __builtin_amdgcn_rcpf(x); }

// paired-rcp: s0/A + s1/B with A=q0*k0+1, B=q1*k1+1
__device__ __forceinline__ void term2(float s0, float s1, float qx, float qy,
                                      float kx, float ky, float& acc) {
    const float A = fmaf(qx, kx, 1.f);
    const float B = fmaf(qy, ky, 1.f);
    acc = fmaf(fmaf(s1, A, s0 * B), fast_rcp(A * B), acc);
}

// ---------------------------------------------------------------------------
// K1: projections + exp transform (unchanged, proven).
// ---------------------------------------------------------------------------
__global__ __launch_bounds__(256) void proj_kernel(
    const float* __restrict__ query, const float* __restrict__ value,
    const float* __restrict__ Wq, const float* __restrict__ Wv,
    float* __restrict__ eq, float* __restrict__ ek)
{
    __shared__ float in_lds[8 * 256];
    const int t = threadIdx.x;
    const int row0 = blockIdx.x * 8;
    const float* src; const float* W; float* dst;
    if (row0 < 2048) { src = query + (size_t)row0 * 256; W = Wq; dst = eq + (size_t)row0 * 256; }
    else { const int r = row0 - 2048; src = value + (size_t)r * 256; W = Wv; dst = ek + (size_t)r * 256; }

    const float4* s4 = (const float4*)src;
    float4* l4 = (float4*)in_lds;
    l4[t] = s4[t];
    l4[t + 256] = s4[t + 256];
    __syncthreads();

    float acc[8];
#pragma unroll
    for (int r = 0; r < 8; ++r) acc[r] = 0.f;

    for (int d = 0; d < 256; d += 4) {
        const float w0 = W[(d + 0) * 256 + t];
        const float w1 = W[(d + 1) * 256 + t];
        const float w2 = W[(d + 2) * 256 + t];
        const float w3 = W[(d + 3) * 256 + t];
#pragma unroll
        for (int r = 0; r < 8; ++r) {
            const float4 v = *(const float4*)&in_lds[r * 256 + d];
            acc[r] = fmaf(v.x, w0, acc[r]);
            acc[r] = fmaf(v.y, w1, acc[r]);
            acc[r] = fmaf(v.z, w2, acc[r]);
            acc[r] = fmaf(v.w, w3, acc[r]);
        }
    }
#pragma unroll
    for (int r = 0; r < 8; ++r) dst[r * 256 + t] = fast_exp2(acc[r] * TWO_LOG2E);
}

// ---------------------------------------------------------------------------
// K2: FUSED scores + softmax + PV, v5: 1024 threads (16 waves = 4/SIMD).
// Block = (b, 8 q-rows), grid (64,4) = 256 blocks.
// Wave w = (oct = w>>1: 32-d octant, qh = w&1: 4 q-rows).
// Lane = (dd = lane>>5: 16-d subsector, qp = (lane>>4)&1, kq = lane&15).
// Register tile 2q x 4k x 4d -> 7 b128 per 32 elems (R13 issue efficiency),
// half the per-wave work, twice the waves -> same total issue, 2x overlap.
// dd-halves combined with one shfl_xor(.,32) per acc; octant partials via
// pslot + deterministic sum (R13-proven). Rotate swizzle (0 conflicts, R13).
// LDS ~109KB -> 1 block/CU (grid forces 1 anyway).
// ---------------------------------------------------------------------------
#define EK_ST 260
#define EQ_ST 260
#define SS_ST 520
#define PS_ST 520
__global__ __launch_bounds__(1024) void fused_kernel(
    const float* __restrict__ eq, const float* __restrict__ ek,
    const float* __restrict__ scale, const float* __restrict__ value,
    float* __restrict__ attn, float* __restrict__ out)
{
    __shared__ float ek_lds[64 * EK_ST];    // 66.6KB; reduce buffer in Phase D
    __shared__ float eq_lds[8 * EQ_ST];     // 8.3KB
    __shared__ float sc_lds[256];
    __shared__ float s_tile[8 * SS_ST];     // 16.6KB raw scores -> raw exp
    __shared__ float pslot[8 * PS_ST];      // 16.6KB octant partials
    __shared__ float inv_lds[8];

    const int t = threadIdx.x;
    const int w = t >> 6, lane = t & 63;
    const int oct = w >> 1, qh = w & 1;
    const int dd = lane >> 5, qp = (lane >> 4) & 1, kq = lane & 15;
    const int qt = blockIdx.x, b = blockIdx.y;
    const int q0 = qt * 8;

    const float4* ekb4 = (const float4*)(ek + (size_t)(b * 512) * 256);

    // prologue: stage eq (8x256 = 512 float4s), scale, ek tile 0
    if (t < 512) {
        const int row = t >> 6, c = t & 63;
        const float4 v = ((const float4*)(eq + (size_t)(b * 512 + q0) * 256))[row * 64 + c];
        *(float4*)&eq_lds[row * EQ_ST + 4 * c] = v;
    } else if (t < 768) {
        sc_lds[t - 512] = -2.f * scale[t - 512];
    }
    {
#pragma unroll
        for (int l = 0; l < 4; ++l) {
            const int row = w + 16 * l;
            const int cc = (lane + (row >> 2)) & 63;
            *(float4*)&ek_lds[row * EK_ST + 4 * cc] = ekb4[(size_t)row * 64 + lane];
        }
    }
    __syncthreads();

    const int qr0 = 4 * qh + 2 * qp;        // first of this thread's 2 q-rows
    const float* eqr0 = &eq_lds[(qr0 + 0) * EQ_ST];
    const float* eqr1 = &eq_lds[(qr0 + 1) * EQ_ST];

    // ---- Phase A: 8 k-tiles ----
    for (int tt = 0; tt < 8; ++tt) {
        float a00 = 0.f, a01 = 0.f, a02 = 0.f, a03 = 0.f;
        float a10 = 0.f, a11 = 0.f, a12 = 0.f, a13 = 0.f;

#pragma unroll
        for (int it = 0; it < 4; ++it) {
            const int d = 32 * oct + 16 * dd + 4 * it;
            const float4 sv  = *(const float4*)&sc_lds[d];
            const float4 q0v = *(const float4*)&eqr0[d];
            const float4 q1v = *(const float4*)&eqr1[d];
            const int cc = 4 * (((d >> 2) + kq) & 63);
            const float4 k0 = *(const float4*)&ek_lds[(4 * kq + 0) * EK_ST + cc];
            const float4 k1 = *(const float4*)&ek_lds[(4 * kq + 1) * EK_ST + cc];
            const float4 k2 = *(const float4*)&ek_lds[(4 * kq + 2) * EK_ST + cc];
            const float4 k3 = *(const float4*)&ek_lds[(4 * kq + 3) * EK_ST + cc];

            term2(sv.x, sv.y, q0v.x, q0v.y, k0.x, k0.y, a00);
            term2(sv.x, sv.y, q0v.x, q0v.y, k1.x, k1.y, a01);
            term2(sv.x, sv.y, q0v.x, q0v.y, k2.x, k2.y, a02);
            term2(sv.x, sv.y, q0v.x, q0v.y, k3.x, k3.y, a03);
            term2(sv.x, sv.y, q1v.x, q1v.y, k0.x, k0.y, a10);
            term2(sv.x, sv.y, q1v.x, q1v.y, k1.x, k1.y, a11);
            term2(sv.x, sv.y, q1v.x, q1v.y, k2.x, k2.y, a12);
            term2(sv.x, sv.y, q1v.x, q1v.y, k3.x, k3.y, a13);

            term2(sv.z, sv.w, q0v.z, q0v.w, k0.z, k0.w, a00);
            term2(sv.z, sv.w, q0v.z, q0v.w, k1.z, k1.w, a01);
            term2(sv.z, sv.w, q0v.z, q0v.w, k2.z, k2.w, a02);
            term2(sv.z, sv.w, q0v.z, q0v.w, k3.z, k3.w, a03);
            term2(sv.z, sv.w, q1v.z, q1v.w, k0.z, k0.w, a10);
            term2(sv.z, sv.w, q1v.z, q1v.w, k1.z, k1.w, a11);
            term2(sv.z, sv.w, q1v.z, q1v.w, k2.z, k2.w, a12);
            term2(sv.z, sv.w, q1v.z, q1v.w, k3.z, k3.w, a13);
        }

        // combine dd-subsectors in-register (lane ^ 32)
        a00 += __shfl_xor(a00, 32); a01 += __shfl_xor(a01, 32);
        a02 += __shfl_xor(a02, 32); a03 += __shfl_xor(a03, 32);
        a10 += __shfl_xor(a10, 32); a11 += __shfl_xor(a11, 32);
        a12 += __shfl_xor(a12, 32); a13 += __shfl_xor(a13, 32);

        if (dd == 0) {
            float* ps = &pslot[oct * PS_ST];
            const int s0i = (qr0 + 0) * 64 + 4 * kq;
            const int s1i = (qr0 + 1) * 64 + 4 * kq;
            ps[s0i + 0] = a00; ps[s0i + 1] = a01; ps[s0i + 2] = a02; ps[s0i + 3] = a03;
            ps[s1i + 0] = a10; ps[s1i + 1] = a11; ps[s1i + 2] = a12; ps[s1i + 3] = a13;
        }
        __syncthreads();                    // pslot complete; ek reads done

        if (tt < 7) {                       // stage next tile (overlaps combine)
            const float4* src = ekb4 + (size_t)(64 * (tt + 1)) * 64;
#pragma unroll
            for (int l = 0; l < 4; ++l) {
                const int row = w + 16 * l;
                const int cc = (lane + (row >> 2)) & 63;
                *(float4*)&ek_lds[row * EK_ST + 4 * cc] = src[(size_t)row * 64 + lane];
            }
        }
        if (t < 512) {                      // deterministic octant sum
            float s = pslot[t];
#pragma unroll
            for (int o = 1; o < 8; ++o) s += pslot[o * PS_ST + t];
            s_tile[(t >> 6) * SS_ST + 64 * tt + (t & 63)] = s;
        }
        __syncthreads();                    // staged + combined
    }

    // ---- Phase B: softmax (waves 0..7, wave = q-row) ----
    if (w < 8) {
        float x[8];
        float m = -1e30f;
#pragma unroll
        for (int j = 0; j < 8; ++j) {
            x[j] = s_tile[w * SS_ST + 64 * j + lane];
            m = fmaxf(m, x[j]);
        }
#pragma unroll
        for (int off = 32; off; off >>= 1) m = fmaxf(m, __shfl_xor(m, off));

        float sum = 0.f;
#pragma unroll
        for (int j = 0; j < 8; ++j) { x[j] = fast_exp2((x[j] - m) * LOG2E); sum += x[j]; }
#pragma unroll
        for (int off = 32; off; off >>= 1) sum += __shfl_xor(sum, off);
        const float inv = fast_rcp(sum);

        float* arow = attn + (size_t)(b * 512 + q0 + w) * 512;
#pragma unroll
        for (int j = 0; j < 8; ++j) {
            s_tile[w * SS_ST + 64 * j + lane] = x[j];   // raw exp for PV
            arow[64 * j + lane] = x[j] * inv;
        }
        if (lane == 0) inv_lds[w] = inv;
    }
    __syncthreads();

    // ---- Phase C: PV, wave w owns k in [32w, 32w+32) ----
    float4 acc[8];
#pragma unroll
    for (int r = 0; r < 8; ++r) acc[r] = make_float4(0.f, 0.f, 0.f, 0.f);

    const float* vbase = value + (size_t)(b * 512 + 32 * w) * 256;
    for (int k4 = 0; k4 < 32; k4 += 4) {
        const float4 v0 = *(const float4*)&vbase[(k4 + 0) * 256 + lane * 4];
        const float4 v1 = *(const float4*)&vbase[(k4 + 1) * 256 + lane * 4];
        const float4 v2 = *(const float4*)&vbase[(k4 + 2) * 256 + lane * 4];
        const float4 v3 = *(const float4*)&vbase[(k4 + 3) * 256 + lane * 4];
#pragma unroll
        for (int r = 0; r < 8; ++r) {
            const float4 s4 = *(const float4*)&s_tile[r * SS_ST + 32 * w + k4];
            acc[r].x = fmaf(s4.x, v0.x, acc[r].x); acc[r].y = fmaf(s4.x, v0.y, acc[r].y);
            acc[r].z = fmaf(s4.x, v0.z, acc[r].z); acc[r].w = fmaf(s4.x, v0.w, acc[r].w);
            acc[r].x = fmaf(s4.y, v1.x, acc[r].x); acc[r].y = fmaf(s4.y, v1.y, acc[r].y);
            acc[r].z = fmaf(s4.y, v1.z, acc[r].z); acc[r].w = fmaf(s4.y, v1.w, acc[r].w);
            acc[r].x = fmaf(s4.z, v2.x, acc[r].x); acc[r].y = fmaf(s4.z, v2.y, acc[r].y);
            acc[r].z = fmaf(s4.z, v2.z, acc[r].z); acc[r].w = fmaf(s4.z, v2.w, acc[r].w);
            acc[r].x = fmaf(s4.w, v3.x, acc[r].x); acc[r].y = fmaf(s4.w, v3.y, acc[r].y);
            acc[r].z = fmaf(s4.w, v3.z, acc[r].z); acc[r].w = fmaf(s4.w, v3.w, acc[r].w);
        }
    }

    // ---- Phase D: tree reduce 16 -> 1 (red = ek_lds, 16640 >= 16384) ----
    float* red = ek_lds;
    if (w >= 8) {
#pragma unroll
        for (int r = 0; r < 8; ++r)
            *(float4*)&red[((w - 8) * 8 + r) * 256 + lane * 4] = acc[r];
    }
    __syncthreads();
    if (w < 8) {
#pragma unroll
        for (int r = 0; r < 8; ++r) {
            const float4 o = *(const float4*)&red[(w * 8 + r) * 256 + lane * 4];
            acc[r].x += o.x; acc[r].y += o.y; acc[r].z += o.z; acc[r].w += o.w;
        }
    }
    __syncthreads();
    if (w >= 4 && w < 8) {
#pragma unroll
        for (int r = 0; r < 8; ++r)
            *(float4*)&red[((w - 4) * 8 + r) * 256 + lane * 4] = acc[r];
    }
    __syncthreads();
    if (w < 4) {
#pragma unroll
        for (int r = 0; r < 8; ++r) {
            const float4 o = *(const float4*)&red[(w * 8 + r) * 256 + lane * 4];
            acc[r].x += o.x; acc[r].y += o.y; acc[r].z += o.z; acc[r].w += o.w;
        }
    }
    __syncthreads();
    if (w >= 2 && w < 4) {
#pragma unroll
        for (int r = 0; r < 8; ++r)
            *(float4*)&red[((w - 2) * 8 + r) * 256 + lane * 4] = acc[r];
    }
    __syncthreads();
    if (w < 2) {
#pragma unroll
        for (int r = 0; r < 8; ++r) {
            const float4 o = *(const float4*)&red[(w * 8 + r) * 256 + lane * 4];
            acc[r].x += o.x; acc[r].y += o.y; acc[r].z += o.z; acc[r].w += o.w;
        }
    }
    __syncthreads();
    if (w == 1) {
#pragma unroll
        for (int r = 0; r < 8; ++r)
            *(float4*)&red[r * 256 + lane * 4] = acc[r];
    }
    __syncthreads();
    if (w == 0) {
#pragma unroll
        for (int r = 0; r < 8; ++r) {
            const float4 o = *(const float4*)&red[r * 256 + lane * 4];
            const float iv = inv_lds[r];
            float4 res;
            res.x = (acc[r].x + o.x) * iv;
            res.y = (acc[r].y + o.y) * iv;
            res.z = (acc[r].z + o.z) * iv;
            res.w = (acc[r].w + o.w) * iv;
            *(float4*)&out[(size_t)(b * 512 + q0 + r) * 256 + lane * 4] = res;
        }
    }
}

extern "C" void kernel_launch(void* const* d_in, const int* in_sizes, int n_in,
                              void* d_out, int out_size, void* d_ws, size_t ws_size,
                              hipStream_t stream) {
    const float* query = (const float*)d_in[0];
    const float* value = (const float*)d_in[1];
    const float* Wq    = (const float*)d_in[2];
    const float* Wv    = (const float*)d_in[3];
    const float* scale = (const float*)d_in[4];

    float* out0 = (float*)d_out;                 // [4,512,256]
    float* attn = out0 + 4 * 512 * 256;          // [4,512,512]

    float* eq = (float*)d_ws;                    // [2048,256]
    float* ek = eq + 2048 * 256;                 // [2048,256]

    proj_kernel<<<512, 256, 0, stream>>>(query, value, Wq, Wv, eq, ek);
    fused_kernel<<<dim3(64, 4), 1024, 0, stream>>>(eq, ek, scale, value, attn, out0);
}

// Round 17
// 66.318 us; speedup vs baseline: 1.0423x; 1.0191x over previous
//
#include <hip/hip_runtime.h>

#define LOG2E 1.4426950408889634f
#define TWO_LOG2E 2.885390081777927f

__device__ __forceinline__ float fast_exp2(float x) { return __builtin_amdgcn_exp2f(x); }
__device__ __forceinline__ float fast_rcp(float x)  { return __builtin_amdgcn_rcpf(x); }

// paired-rcp: s0/A + s1/B with A=q0*k0+1, B=q1*k1+1
__device__ __forceinline__ void term2(float s0, float s1, float qx, float qy,
                                      float kx, float ky, float& acc) {
    const float A = fmaf(qx, kx, 1.f);
    const float B = fmaf(qy, ky, 1.f);
    acc = fmaf(fmaf(s1, A, s0 * B), fast_rcp(A * B), acc);
}

// ---------------------------------------------------------------------------
// K1: projections + exp transform (unchanged, proven).
// ---------------------------------------------------------------------------
__global__ __launch_bounds__(256) void proj_kernel(
    const float* __restrict__ query, const float* __restrict__ value,
    const float* __restrict__ Wq, const float* __restrict__ Wv,
    float* __restrict__ eq, float* __restrict__ ek)
{
    __shared__ float in_lds[8 * 256];
    const int t = threadIdx.x;
    const int row0 = blockIdx.x * 8;
    const float* src; const float* W; float* dst;
    if (row0 < 2048) { src = query + (size_t)row0 * 256; W = Wq; dst = eq + (size_t)row0 * 256; }
    else { const int r = row0 - 2048; src = value + (size_t)r * 256; W = Wv; dst = ek + (size_t)r * 256; }

    const float4* s4 = (const float4*)src;
    float4* l4 = (float4*)in_lds;
    l4[t] = s4[t];
    l4[t + 256] = s4[t + 256];
    __syncthreads();

    float acc[8];
#pragma unroll
    for (int r = 0; r < 8; ++r) acc[r] = 0.f;

    for (int d = 0; d < 256; d += 4) {
        const float w0 = W[(d + 0) * 256 + t];
        const float w1 = W[(d + 1) * 256 + t];
        const float w2 = W[(d + 2) * 256 + t];
        const float w3 = W[(d + 3) * 256 + t];
#pragma unroll
        for (int r = 0; r < 8; ++r) {
            const float4 v = *(const float4*)&in_lds[r * 256 + d];
            acc[r] = fmaf(v.x, w0, acc[r]);
            acc[r] = fmaf(v.y, w1, acc[r]);
            acc[r] = fmaf(v.z, w2, acc[r]);
            acc[r] = fmaf(v.w, w3, acc[r]);
        }
    }
#pragma unroll
    for (int r = 0; r < 8; ++r) dst[r * 256 + t] = fast_exp2(acc[r] * TWO_LOG2E);
}

// ---------------------------------------------------------------------------
// K2: FUSED scores + softmax + PV, v6: v5 + pipeline fixes.
//  - __launch_bounds__(1024,4): VGPR cap 128 (was compiler-throttled to 64 ->
//    no load prefetch -> LDS/VALU pipes serialized, VALUBusy 46%).
//  - it-loop software-pipelined: it+1's 7 b128 loads issued while computing it.
//  - T14 async-stage: next tile's 4 global b128 issued BEFORE compute,
//    ds_write after the barrier (global latency hidden under compute).
// Structure/addressing identical to v5 (verified: 0 bank conflicts, correct).
// ---------------------------------------------------------------------------
#define EK_ST 260
#define EQ_ST 260
#define SS_ST 520
#define PS_ST 520
__global__ __launch_bounds__(1024, 4) void fused_kernel(
    const float* __restrict__ eq, const float* __restrict__ ek,
    const float* __restrict__ scale, const float* __restrict__ value,
    float* __restrict__ attn, float* __restrict__ out)
{
    __shared__ float ek_lds[64 * EK_ST];    // 66.6KB; reduce buffer in Phase D
    __shared__ float eq_lds[8 * EQ_ST];     // 8.3KB
    __shared__ float sc_lds[256];
    __shared__ float s_tile[8 * SS_ST];     // 16.6KB raw scores -> raw exp
    __shared__ float pslot[8 * PS_ST];      // 16.6KB octant partials
    __shared__ float inv_lds[8];

    const int t = threadIdx.x;
    const int w = t >> 6, lane = t & 63;
    const int oct = w >> 1, qh = w & 1;
    const int dd = lane >> 5, qp = (lane >> 4) & 1, kq = lane & 15;
    const int qt = blockIdx.x, b = blockIdx.y;
    const int q0 = qt * 8;

    const float4* ekb4 = (const float4*)(ek + (size_t)(b * 512) * 256);

    // prologue: stage eq (8x256 = 512 float4s), scale, ek tile 0
    if (t < 512) {
        const int row = t >> 6, c = t & 63;
        const float4 v = ((const float4*)(eq + (size_t)(b * 512 + q0) * 256))[row * 64 + c];
        *(float4*)&eq_lds[row * EQ_ST + 4 * c] = v;
    } else if (t < 768) {
        sc_lds[t - 512] = -2.f * scale[t - 512];
    }
    {
#pragma unroll
        for (int l = 0; l < 4; ++l) {
            const int row = w + 16 * l;
            const int cc = (lane + (row >> 2)) & 63;
            *(float4*)&ek_lds[row * EK_ST + 4 * cc] = ekb4[(size_t)row * 64 + lane];
        }
    }
    __syncthreads();

    const int qr0 = 4 * qh + 2 * qp;        // first of this thread's 2 q-rows
    const float* eqr0 = &eq_lds[(qr0 + 0) * EQ_ST];
    const float* eqr1 = &eq_lds[(qr0 + 1) * EQ_ST];
    const int d0 = 32 * oct + 16 * dd;      // this thread's d-sector base

    // ---- Phase A: 8 k-tiles ----
    for (int tt = 0; tt < 8; ++tt) {
        // T14: issue next tile's global loads FIRST (latency hides under compute)
        float4 g0, g1, g2, g3;
        if (tt < 7) {
            const float4* src = ekb4 + (size_t)(64 * (tt + 1)) * 64;
            g0 = src[(size_t)(w +  0) * 64 + lane];
            g1 = src[(size_t)(w + 16) * 64 + lane];
            g2 = src[(size_t)(w + 32) * 64 + lane];
            g3 = src[(size_t)(w + 48) * 64 + lane];
        }

        float a00 = 0.f, a01 = 0.f, a02 = 0.f, a03 = 0.f;
        float a10 = 0.f, a11 = 0.f, a12 = 0.f, a13 = 0.f;

        // software-pipelined it-loop: preload it=0
        float4 sv, q0v, q1v, k0, k1, k2, k3;
        {
            const int d = d0;
            sv  = *(const float4*)&sc_lds[d];
            q0v = *(const float4*)&eqr0[d];
            q1v = *(const float4*)&eqr1[d];
            const int cc = 4 * (((d >> 2) + kq) & 63);
            k0 = *(const float4*)&ek_lds[(4 * kq + 0) * EK_ST + cc];
            k1 = *(const float4*)&ek_lds[(4 * kq + 1) * EK_ST + cc];
            k2 = *(const float4*)&ek_lds[(4 * kq + 2) * EK_ST + cc];
            k3 = *(const float4*)&ek_lds[(4 * kq + 3) * EK_ST + cc];
        }
#pragma unroll
        for (int it = 0; it < 4; ++it) {
            const float4 csv = sv, cq0 = q0v, cq1 = q1v;
            const float4 ck0 = k0, ck1 = k1, ck2 = k2, ck3 = k3;
            if (it < 3) {                   // prefetch it+1
                const int d = d0 + 4 * (it + 1);
                sv  = *(const float4*)&sc_lds[d];
                q0v = *(const float4*)&eqr0[d];
                q1v = *(const float4*)&eqr1[d];
                const int cc = 4 * (((d >> 2) + kq) & 63);
                k0 = *(const float4*)&ek_lds[(4 * kq + 0) * EK_ST + cc];
                k1 = *(const float4*)&ek_lds[(4 * kq + 1) * EK_ST + cc];
                k2 = *(const float4*)&ek_lds[(4 * kq + 2) * EK_ST + cc];
                k3 = *(const float4*)&ek_lds[(4 * kq + 3) * EK_ST + cc];
            }

            term2(csv.x, csv.y, cq0.x, cq0.y, ck0.x, ck0.y, a00);
            term2(csv.x, csv.y, cq0.x, cq0.y, ck1.x, ck1.y, a01);
            term2(csv.x, csv.y, cq0.x, cq0.y, ck2.x, ck2.y, a02);
            term2(csv.x, csv.y, cq0.x, cq0.y, ck3.x, ck3.y, a03);
            term2(csv.x, csv.y, cq1.x, cq1.y, ck0.x, ck0.y, a10);
            term2(csv.x, csv.y, cq1.x, cq1.y, ck1.x, ck1.y, a11);
            term2(csv.x, csv.y, cq1.x, cq1.y, ck2.x, ck2.y, a12);
            term2(csv.x, csv.y, cq1.x, cq1.y, ck3.x, ck3.y, a13);

            term2(csv.z, csv.w, cq0.z, cq0.w, ck0.z, ck0.w, a00);
            term2(csv.z, csv.w, cq0.z, cq0.w, ck1.z, ck1.w, a01);
            term2(csv.z, csv.w, cq0.z, cq0.w, ck2.z, ck2.w, a02);
            term2(csv.z, csv.w, cq0.z, cq0.w, ck3.z, ck3.w, a03);
            term2(csv.z, csv.w, cq1.z, cq1.w, ck0.z, ck0.w, a10);
            term2(csv.z, csv.w, cq1.z, cq1.w, ck1.z, ck1.w, a11);
            term2(csv.z, csv.w, cq1.z, cq1.w, ck2.z, ck2.w, a12);
            term2(csv.z, csv.w, cq1.z, cq1.w, ck3.z, ck3.w, a13);
        }

        // combine dd-subsectors in-register (lane ^ 32)
        a00 += __shfl_xor(a00, 32); a01 += __shfl_xor(a01, 32);
        a02 += __shfl_xor(a02, 32); a03 += __shfl_xor(a03, 32);
        a10 += __shfl_xor(a10, 32); a11 += __shfl_xor(a11, 32);
        a12 += __shfl_xor(a12, 32); a13 += __shfl_xor(a13, 32);

        if (dd == 0) {
            float* ps = &pslot[oct * PS_ST];
            const int s0i = (qr0 + 0) * 64 + 4 * kq;
            const int s1i = (qr0 + 1) * 64 + 4 * kq;
            ps[s0i + 0] = a00; ps[s0i + 1] = a01; ps[s0i + 2] = a02; ps[s0i + 3] = a03;
            ps[s1i + 0] = a10; ps[s1i + 1] = a11; ps[s1i + 2] = a12; ps[s1i + 3] = a13;
        }
        __syncthreads();                    // ek reads + pslot writes done

        if (tt < 7) {                       // ds_write the prefetched tile
#pragma unroll
            for (int l = 0; l < 4; ++l) {
                const int row = w + 16 * l;
                const int cc = (lane + (row >> 2)) & 63;
                const float4 g = (l == 0) ? g0 : (l == 1) ? g1 : (l == 2) ? g2 : g3;
                *(float4*)&ek_lds[row * EK_ST + 4 * cc] = g;
            }
        }
        if (t < 512) {                      // deterministic octant sum
            float s = pslot[t];
#pragma unroll
            for (int o = 1; o < 8; ++o) s += pslot[o * PS_ST + t];
            s_tile[(t >> 6) * SS_ST + 64 * tt + (t & 63)] = s;
        }
        __syncthreads();                    // staged + combined
    }

    // ---- Phase B: softmax (waves 0..7, wave = q-row) ----
    if (w < 8) {
        float x[8];
        float m = -1e30f;
#pragma unroll
        for (int j = 0; j < 8; ++j) {
            x[j] = s_tile[w * SS_ST + 64 * j + lane];
            m = fmaxf(m, x[j]);
        }
#pragma unroll
        for (int off = 32; off; off >>= 1) m = fmaxf(m, __shfl_xor(m, off));

        float sum = 0.f;
#pragma unroll
        for (int j = 0; j < 8; ++j) { x[j] = fast_exp2((x[j] - m) * LOG2E); sum += x[j]; }
#pragma unroll
        for (int off = 32; off; off >>= 1) sum += __shfl_xor(sum, off);
        const float inv = fast_rcp(sum);

        float* arow = attn + (size_t)(b * 512 + q0 + w) * 512;
#pragma unroll
        for (int j = 0; j < 8; ++j) {
            s_tile[w * SS_ST + 64 * j + lane] = x[j];   // raw exp for PV
            arow[64 * j + lane] = x[j] * inv;
        }
        if (lane == 0) inv_lds[w] = inv;
    }
    __syncthreads();

    // ---- Phase C: PV, wave w owns k in [32w, 32w+32) ----
    float4 acc[8];
#pragma unroll
    for (int r = 0; r < 8; ++r) acc[r] = make_float4(0.f, 0.f, 0.f, 0.f);

    const float* vbase = value + (size_t)(b * 512 + 32 * w) * 256;
    for (int k4 = 0; k4 < 32; k4 += 4) {
        const float4 v0 = *(const float4*)&vbase[(k4 + 0) * 256 + lane * 4];
        const float4 v1 = *(const float4*)&vbase[(k4 + 1) * 256 + lane * 4];
        const float4 v2 = *(const float4*)&vbase[(k4 + 2) * 256 + lane * 4];
        const float4 v3 = *(const float4*)&vbase[(k4 + 3) * 256 + lane * 4];
#pragma unroll
        for (int r = 0; r < 8; ++r) {
            const float4 s4 = *(const float4*)&s_tile[r * SS_ST + 32 * w + k4];
            acc[r].x = fmaf(s4.x, v0.x, acc[r].x); acc[r].y = fmaf(s4.x, v0.y, acc[r].y);
            acc[r].z = fmaf(s4.x, v0.z, acc[r].z); acc[r].w = fmaf(s4.x, v0.w, acc[r].w);
            acc[r].x = fmaf(s4.y, v1.x, acc[r].x); acc[r].y = fmaf(s4.y, v1.y, acc[r].y);
            acc[r].z = fmaf(s4.y, v1.z, acc[r].z); acc[r].w = fmaf(s4.y, v1.w, acc[r].w);
            acc[r].x = fmaf(s4.z, v2.x, acc[r].x); acc[r].y = fmaf(s4.z, v2.y, acc[r].y);
            acc[r].z = fmaf(s4.z, v2.z, acc[r].z); acc[r].w = fmaf(s4.z, v2.w, acc[r].w);
            acc[r].x = fmaf(s4.w, v3.x, acc[r].x); acc[r].y = fmaf(s4.w, v3.y, acc[r].y);
            acc[r].z = fmaf(s4.w, v3.z, acc[r].z); acc[r].w = fmaf(s4.w, v3.w, acc[r].w);
        }
    }

    // ---- Phase D: tree reduce 16 -> 1 (red = ek_lds, 16640 >= 16384) ----
    float* red = ek_lds;
    if (w >= 8) {
#pragma unroll
        for (int r = 0; r < 8; ++r)
            *(float4*)&red[((w - 8) * 8 + r) * 256 + lane * 4] = acc[r];
    }
    __syncthreads();
    if (w < 8) {
#pragma unroll
        for (int r = 0; r < 8; ++r) {
            const float4 o = *(const float4*)&red[(w * 8 + r) * 256 + lane * 4];
            acc[r].x += o.x; acc[r].y += o.y; acc[r].z += o.z; acc[r].w += o.w;
        }
    }
    __syncthreads();
    if (w >= 4 && w < 8) {
#pragma unroll
        for (int r = 0; r < 8; ++r)
            *(float4*)&red[((w - 4) * 8 + r) * 256 + lane * 4] = acc[r];
    }
    __syncthreads();
    if (w < 4) {
#pragma unroll
        for (int r = 0; r < 8; ++r) {
            const float4 o = *(const float4*)&red[(w * 8 + r) * 256 + lane * 4];
            acc[r].x += o.x; acc[r].y += o.y; acc[r].z += o.z; acc[r].w += o.w;
        }
    }
    __syncthreads();
    if (w >= 2 && w < 4) {
#pragma unroll
        for (int r = 0; r < 8; ++r)
            *(float4*)&red[((w - 2) * 8 + r) * 256 + lane * 4] = acc[r];
    }
    __syncthreads();
    if (w < 2) {
#pragma unroll
        for (int r = 0; r < 8; ++r) {
            const float4 o = *(const float4*)&red[(w * 8 + r) * 256 + lane * 4];
            acc[r].x += o.x; acc[r].y += o.y; acc[r].z += o.z; acc[r].w += o.w;
        }
    }
    __syncthreads();
    if (w == 1) {
#pragma unroll
        for (int r = 0; r < 8; ++r)
            *(float4*)&red[r * 256 + lane * 4] = acc[r];
    }
    __syncthreads();
    if (w == 0) {
#pragma unroll
        for (int r = 0; r < 8; ++r) {
            const float4 o = *(const float4*)&red[r * 256 + lane * 4];
            const float iv = inv_lds[r];
            float4 res;
            res.x = (acc[r].x + o.x) * iv;
            res.y = (acc[r].y + o.y) * iv;
            res.z = (acc[r].z + o.z) * iv;
            res.w = (acc[r].w + o.w) * iv;
            *(float4*)&out[(size_t)(b * 512 + q0 + r) * 256 + lane * 4] = res;
        }
    }
}

extern "C" void kernel_launch(void* const* d_in, const int* in_sizes, int n_in,
                              void* d_out, int out_size, void* d_ws, size_t ws_size,
                              hipStream_t stream) {
    const float* query = (const float*)d_in[0];
    const float* value = (const float*)d_in[1];
    const float* Wq    = (const float*)d_in[2];
    const float* Wv    = (const float*)d_in[3];
    const float* scale = (const float*)d_in[4];

    float* out0 = (float*)d_out;                 // [4,512,256]
    float* attn = out0 + 4 * 512 * 256;          // [4,512,512]

    float* eq = (float*)d_ws;                    // [2048,256]
    float* ek = eq + 2048 * 256;                 // [2048,256]

    proj_kernel<<<512, 256, 0, stream>>>(query, value, Wq, Wv, eq, ek);
    fused_kernel<<<dim3(64, 4), 1024, 0, stream>>>(eq, ek, scale, value, attn, out0);
}